// Round 1
// baseline (1062.027 us; speedup 1.0000x reference)
//
#include <hip/hip_runtime.h>

#define CAP 64
#define DD 48

// ---------------- adjacency build (dst-bucketed, fixed capacity) ----------------
__global__ void build_adj_kernel(const int* __restrict__ ei, int E, int N,
                                 int* __restrict__ cnt, int* __restrict__ adj) {
    int e = blockIdx.x * blockDim.x + threadIdx.x;
    int Et = E + N;
    if (e >= Et) return;
    int s, d;
    if (e < E) { s = ei[e]; d = ei[E + e]; } else { s = e - E; d = e - E; }
    int pos = atomicAdd(&cnt[d], 1);
    if (pos < CAP) adj[d * CAP + pos] = s;
}

// ---------------- fp32 tiled GEMM: Hout[N,NCT] = X[N,K] @ W[K,NCT] ----------------
// block tile 64 rows x 96 cols, K-tile 32, 256 threads (16x16), thread tile 4x6
template<int K, int NCT>
__global__ void gemm_kernel(const float* __restrict__ X, const float* __restrict__ W,
                            float* __restrict__ Hout, int N) {
    __shared__ float XT[32][64];   // k-major x-tile (transposed)
    __shared__ float WS[32][96];
    int tid = threadIdx.x;
    int ty = tid >> 4, tx = tid & 15;
    int rb = blockIdx.x * 64;
    int c0 = blockIdx.y * 96;
    float acc[4][6];
#pragma unroll
    for (int i = 0; i < 4; i++)
#pragma unroll
        for (int j = 0; j < 6; j++) acc[i][j] = 0.f;

    for (int k0 = 0; k0 < K; k0 += 32) {
#pragma unroll
        for (int jj = 0; jj < 2; jj++) {          // 64x32 X tile, 2 float4/thread
            int idx = tid + jj * 256;
            int r = idx >> 3, kq = idx & 7;
            int rg = rb + r;
            float4 v = make_float4(0.f, 0.f, 0.f, 0.f);
            if (rg < N) v = *reinterpret_cast<const float4*>(&X[(long)rg * K + k0 + kq * 4]);
            XT[kq * 4 + 0][r] = v.x; XT[kq * 4 + 1][r] = v.y;
            XT[kq * 4 + 2][r] = v.z; XT[kq * 4 + 3][r] = v.w;
        }
#pragma unroll
        for (int jj = 0; jj < 3; jj++) {          // 32x96 W tile, 3 float4/thread
            int idx = tid + jj * 256;
            int kr = idx / 24, cq = idx % 24;
            float4 v = *reinterpret_cast<const float4*>(&W[(long)(k0 + kr) * NCT + c0 + cq * 4]);
            *reinterpret_cast<float4*>(&WS[kr][cq * 4]) = v;
        }
        __syncthreads();
#pragma unroll
        for (int kk = 0; kk < 32; kk++) {
            float a[4], b[6];
#pragma unroll
            for (int i = 0; i < 4; i++) a[i] = XT[kk][ty * 4 + i];
#pragma unroll
            for (int j = 0; j < 6; j++) b[j] = WS[kk][tx * 6 + j];
#pragma unroll
            for (int i = 0; i < 4; i++)
#pragma unroll
                for (int j = 0; j < 6; j++) acc[i][j] = fmaf(a[i], b[j], acc[i][j]);
        }
        __syncthreads();
    }
#pragma unroll
    for (int i = 0; i < 4; i++) {
        int r = rb + ty * 4 + i;
        if (r < N) {
#pragma unroll
            for (int j = 0; j < 6; j++)
                Hout[(long)r * NCT + c0 + tx * 6 + j] = acc[i][j];
        }
    }
}

// ---------------- per-(node,head) attention dots ----------------
template<int HEADS, int NCT>
__global__ void attdot_kernel(const float* __restrict__ H, const float* __restrict__ att_s,
                              const float* __restrict__ att_d, float* __restrict__ asrc,
                              float* __restrict__ adst, int N) {
    int idx = blockIdx.x * blockDim.x + threadIdx.x;
    if (idx >= N * HEADS) return;
    int n = idx / HEADS, h = idx % HEADS;
    const float* row = &H[(long)n * (HEADS * DD) + h * DD];
    float s1 = 0.f, s2 = 0.f;
#pragma unroll
    for (int d = 0; d < DD; d++) {
        float v = row[d];
        s1 = fmaf(v, att_s[h * DD + d], s1);
        s2 = fmaf(v, att_d[h * DD + d], s2);
    }
    asrc[idx] = s1;
    adst[idx] = s2;
}

// ---------------- dst-centric fused softmax + aggregate + bias + relu ----------------
// one wave per node; lane owns channels {lane, lane+64, lane+128} ∩ [0,OUT)
template<int OUT, int HEADS>
__global__ void agg_kernel(const float* __restrict__ Hin, const float* __restrict__ asrc,
                           const float* __restrict__ adst, const int* __restrict__ adj,
                           const int* __restrict__ cnt, const float* __restrict__ bias,
                           float* __restrict__ Oout, int N) {
    int gtid = blockIdx.x * blockDim.x + threadIdx.x;
    int n = gtid >> 6;
    int lane = gtid & 63;
    if (n >= N) return;
    constexpr int J = (OUT + 63) / 64;
    float acc[J], den[J], adn[J];
    int hd[J];
#pragma unroll
    for (int j = 0; j < J; j++) {
        acc[j] = 0.f; den[j] = 0.f; hd[j] = 0; adn[j] = 0.f;
        int c = lane + 64 * j;
        if (c < OUT) { hd[j] = c / DD; adn[j] = adst[n * HEADS + hd[j]]; }
    }
    int deg = cnt[n]; if (deg > CAP) deg = CAP;
    for (int i = 0; i < deg; i++) {
        int s = adj[n * CAP + i];
#pragma unroll
        for (int j = 0; j < J; j++) {
            int c = lane + 64 * j;
            if (c < OUT) {
                float e = asrc[s * HEADS + hd[j]] + adn[j];
                e = (e < 0.f) ? 0.2f * e : e;       // leaky_relu, slope 0.2
                float w = __expf(e);                // max-shift dropped: alpha scale-invariant
                den[j] += w;
                acc[j] = fmaf(w, Hin[(long)s * OUT + c], acc[j]);
            }
        }
    }
#pragma unroll
    for (int j = 0; j < J; j++) {
        int c = lane + 64 * j;
        if (c < OUT) {
            float o = acc[j] / (den[j] + 1e-16f) + bias[c];
            Oout[(long)n * OUT + c] = fmaxf(o, 0.f);
        }
    }
}

// ---------------- mean-pool stage 1 (batch is sorted: register-accumulate, flush on change) ----------------
__global__ void pool_kernel(const float* __restrict__ O, const int* __restrict__ batch,
                            float* __restrict__ sums, float* __restrict__ counts, int N) {
    int tid = threadIdx.x;                     // 128 threads
    int n0 = blockIdx.x * 512;
    if (n0 >= N) return;
    int nend = min(N, n0 + 512);
    float acc = 0.f; int cl = 0;
    int cur = batch[n0];
    for (int n = n0; n < nend; n++) {
        int g = batch[n];
        if (g != cur) {
            if (tid < 96) atomicAdd(&sums[cur * 96 + tid], acc);
            if (tid == 96) atomicAdd(&counts[cur], (float)cl);
            acc = 0.f; cl = 0; cur = g;
        }
        if (tid < 96) acc += O[(long)n * 96 + tid];
        cl++;
    }
    if (tid < 96) atomicAdd(&sums[cur * 96 + tid], acc);
    if (tid == 96) atomicAdd(&counts[cur], (float)cl);
}

// ---------------- FC head: one block per graph ----------------
__global__ void fc_kernel(const float* __restrict__ sums, const float* __restrict__ counts,
                          const float* __restrict__ W1, const float* __restrict__ b1,
                          const float* __restrict__ W2, const float* __restrict__ b2,
                          float* __restrict__ out) {
    __shared__ float p[96];
    __shared__ float h1[192];
    int g = blockIdx.x, tid = threadIdx.x;     // 192 threads
    if (tid < 96) p[tid] = sums[g * 96 + tid] / fmaxf(counts[g], 1.0f);
    __syncthreads();
    float s = b1[tid];
    for (int c = 0; c < 96; c++) s = fmaf(p[c], W1[c * 192 + tid], s);
    h1[tid] = fmaxf(s, 0.f);
    __syncthreads();
    if (tid < 96) {
        float s2 = b2[tid];
        for (int j = 0; j < 192; j++) s2 = fmaf(h1[j], W2[j * 96 + tid], s2);
        out[g * 96 + tid] = s2;
    }
}

extern "C" void kernel_launch(void* const* d_in, const int* in_sizes, int n_in,
                              void* d_out, int out_size, void* d_ws, size_t ws_size,
                              hipStream_t stream) {
    const float* x     = (const float*)d_in[0];
    const int*   ei    = (const int*)d_in[1];
    const int*   batch = (const int*)d_in[2];
    const float* W0  = (const float*)d_in[3];
    const float* as0 = (const float*)d_in[4];
    const float* ad0 = (const float*)d_in[5];
    const float* b0  = (const float*)d_in[6];
    const float* W1  = (const float*)d_in[7];
    const float* as1 = (const float*)d_in[8];
    const float* ad1 = (const float*)d_in[9];
    const float* b1  = (const float*)d_in[10];
    const float* W2  = (const float*)d_in[11];
    const float* as2 = (const float*)d_in[12];
    const float* ad2 = (const float*)d_in[13];
    const float* b2  = (const float*)d_in[14];
    const float* fcW1 = (const float*)d_in[15];
    const float* fcb1 = (const float*)d_in[16];
    const float* fcW2 = (const float*)d_in[17];
    const float* fcb2 = (const float*)d_in[18];

    const int N = in_sizes[0] / 128;
    const int E = in_sizes[1] / 2;

    char* ws = (char*)d_ws;
    float* Hbuf = (float*)ws;                                   // N*192 f
    float* Obuf = (float*)(ws + (size_t)N * 192 * 4);           // N*192 f
    float* ASRC = (float*)(ws + (size_t)N * 384 * 4);           // N*4 f
    float* ADST = ASRC + (size_t)N * 4;                         // N*4 f
    int*   ADJ  = (int*)(ADST + (size_t)N * 4);                 // N*CAP i
    int*   CNT  = ADJ + (size_t)N * CAP;                        // N i
    float* SUMS = (float*)(CNT + N);                            // 64*96 f
    float* COUNTS = SUMS + 64 * 96;                             // 64 f

    // zero: CNT + SUMS + COUNTS (contiguous)
    hipMemsetAsync(CNT, 0, ((size_t)N + 64 * 96 + 64) * 4, stream);

    int Et = E + N;
    build_adj_kernel<<<(Et + 255) / 256, 256, 0, stream>>>(ei, E, N, CNT, ADJ);

    int rb = (N + 63) / 64;

    // layer 0: 128 -> 4x48
    gemm_kernel<128, 192><<<dim3(rb, 2), 256, 0, stream>>>(x, W0, Hbuf, N);
    attdot_kernel<4, 192><<<(N * 4 + 255) / 256, 256, 0, stream>>>(Hbuf, as0, ad0, ASRC, ADST, N);
    agg_kernel<192, 4><<<(N + 3) / 4, 256, 0, stream>>>(Hbuf, ASRC, ADST, ADJ, CNT, b0, Obuf, N);

    // layer 1: 192 -> 2x48
    gemm_kernel<192, 96><<<dim3(rb, 1), 256, 0, stream>>>(Obuf, W1, Hbuf, N);
    attdot_kernel<2, 96><<<(N * 2 + 255) / 256, 256, 0, stream>>>(Hbuf, as1, ad1, ASRC, ADST, N);
    agg_kernel<96, 2><<<(N + 3) / 4, 256, 0, stream>>>(Hbuf, ASRC, ADST, ADJ, CNT, b1, Obuf, N);

    // layer 2: 96 -> 2x48
    gemm_kernel<96, 96><<<dim3(rb, 1), 256, 0, stream>>>(Obuf, W2, Hbuf, N);
    attdot_kernel<2, 96><<<(N * 2 + 255) / 256, 256, 0, stream>>>(Hbuf, as2, ad2, ASRC, ADST, N);
    agg_kernel<96, 2><<<(N + 3) / 4, 256, 0, stream>>>(Hbuf, ASRC, ADST, ADJ, CNT, b2, Obuf, N);

    // pooling + FC head
    pool_kernel<<<(N + 511) / 512, 128, 0, stream>>>(Obuf, batch, SUMS, COUNTS, N);
    fc_kernel<<<64, 192, 0, stream>>>(SUMS, COUNTS, fcW1, fcb1, fcW2, fcb2, (float*)d_out);
}

// Round 2
// 872.660 us; speedup vs baseline: 1.2170x; 1.2170x over previous
//
#include <hip/hip_runtime.h>

#define CAP 64
#define DD 48

// ---------------- adjacency build (dst-bucketed, fixed capacity) ----------------
__global__ void build_adj_kernel(const int* __restrict__ ei, int E, int N,
                                 int* __restrict__ cnt, int* __restrict__ adj) {
    int e = blockIdx.x * blockDim.x + threadIdx.x;
    int Et = E + N;
    if (e >= Et) return;
    int s, d;
    if (e < E) { s = ei[e]; d = ei[E + e]; } else { s = e - E; d = e - E; }
    int pos = atomicAdd(&cnt[d], 1);
    if (pos < CAP) adj[d * CAP + pos] = s;
}

// ---------------- fp32 tiled GEMM: Hout[N,NCT] = X[N,K] @ W[K,NCT] ----------------
template<int K, int NCT>
__global__ void gemm_kernel(const float* __restrict__ X, const float* __restrict__ W,
                            float* __restrict__ Hout, int N) {
    __shared__ float XT[32][64];   // k-major x-tile (transposed)
    __shared__ float WS[32][96];
    int tid = threadIdx.x;
    int ty = tid >> 4, tx = tid & 15;
    int rb = blockIdx.x * 64;
    int c0 = blockIdx.y * 96;
    float acc[4][6];
#pragma unroll
    for (int i = 0; i < 4; i++)
#pragma unroll
        for (int j = 0; j < 6; j++) acc[i][j] = 0.f;

    for (int k0 = 0; k0 < K; k0 += 32) {
#pragma unroll
        for (int jj = 0; jj < 2; jj++) {
            int idx = tid + jj * 256;
            int r = idx >> 3, kq = idx & 7;
            int rg = rb + r;
            float4 v = make_float4(0.f, 0.f, 0.f, 0.f);
            if (rg < N) v = *reinterpret_cast<const float4*>(&X[(long)rg * K + k0 + kq * 4]);
            XT[kq * 4 + 0][r] = v.x; XT[kq * 4 + 1][r] = v.y;
            XT[kq * 4 + 2][r] = v.z; XT[kq * 4 + 3][r] = v.w;
        }
#pragma unroll
        for (int jj = 0; jj < 3; jj++) {
            int idx = tid + jj * 256;
            int kr = idx / 24, cq = idx % 24;
            float4 v = *reinterpret_cast<const float4*>(&W[(long)(k0 + kr) * NCT + c0 + cq * 4]);
            *reinterpret_cast<float4*>(&WS[kr][cq * 4]) = v;
        }
        __syncthreads();
#pragma unroll
        for (int kk = 0; kk < 32; kk++) {
            float a[4], b[6];
#pragma unroll
            for (int i = 0; i < 4; i++) a[i] = XT[kk][ty * 4 + i];
#pragma unroll
            for (int j = 0; j < 6; j++) b[j] = WS[kk][tx * 6 + j];
#pragma unroll
            for (int i = 0; i < 4; i++)
#pragma unroll
                for (int j = 0; j < 6; j++) acc[i][j] = fmaf(a[i], b[j], acc[i][j]);
        }
        __syncthreads();
    }
#pragma unroll
    for (int i = 0; i < 4; i++) {
        int r = rb + ty * 4 + i;
        if (r < N) {
#pragma unroll
            for (int j = 0; j < 6; j++)
                Hout[(long)r * NCT + c0 + tx * 6 + j] = acc[i][j];
        }
    }
}

// ---------------- per-(node,head) attention dots ----------------
template<int HEADS, int NCT>
__global__ void attdot_kernel(const float* __restrict__ H, const float* __restrict__ att_s,
                              const float* __restrict__ att_d, float* __restrict__ asrc,
                              float* __restrict__ adst, int N) {
    int idx = blockIdx.x * blockDim.x + threadIdx.x;
    if (idx >= N * HEADS) return;
    int n = idx / HEADS, h = idx % HEADS;
    const float* row = &H[(long)n * (HEADS * DD) + h * DD];
    float s1 = 0.f, s2 = 0.f;
#pragma unroll
    for (int d = 0; d < DD; d++) {
        float v = row[d];
        s1 = fmaf(v, att_s[h * DD + d], s1);
        s2 = fmaf(v, att_d[h * DD + d], s2);
    }
    asrc[idx] = s1;
    adst[idx] = s2;
}

// ---------------- dst-centric fused softmax + aggregate + bias + relu ----------------
// one wave per node. Restructured (R2): one coalesced adjacency load (lane i = edge i),
// per-edge per-head weight computed ONCE (HEADS exps/edge, not 64*J), broadcast via
// per-wave LDS region; inner loop is only independent Hin row-gathers, unrolled x4.
template<int OUT, int HEADS>
__global__ void agg_kernel(const float* __restrict__ Hin, const float* __restrict__ asrc,
                           const float* __restrict__ adst, const int* __restrict__ adj,
                           const int* __restrict__ cnt, const float* __restrict__ bias,
                           float* __restrict__ Oout, int N) {
    constexpr int J = (OUT + 63) / 64;
    __shared__ float wlds[4][HEADS][CAP];
    __shared__ int   slds[4][CAP];
    int wv = threadIdx.x >> 6;
    int lane = threadIdx.x & 63;
    int n = blockIdx.x * 4 + wv;
    bool valid = (n < N);
    int nn = valid ? n : 0;
    int deg = min(cnt[nn], CAP);
    int s = (lane < deg) ? adj[nn * CAP + lane] : 0;
    slds[wv][lane] = s;
    if (lane < deg) {
#pragma unroll
        for (int h = 0; h < HEADS; h++) {
            float e = asrc[s * HEADS + h] + adst[nn * HEADS + h];
            e = (e < 0.f) ? 0.2f * e : e;           // leaky_relu, slope 0.2
            wlds[wv][h][lane] = __expf(e);          // max-shift dropped: alpha scale-invariant
        }
    }
    __syncthreads();

    float acc[J], den[J];
    int hd[J], cc[J];
#pragma unroll
    for (int j = 0; j < J; j++) {
        acc[j] = 0.f; den[j] = 0.f;
        cc[j] = lane + 64 * j; hd[j] = cc[j] / DD;
    }
    int i = 0;
    for (; i + 4 <= deg; i += 4) {
        int s0 = slds[wv][i], s1 = slds[wv][i + 1], s2 = slds[wv][i + 2], s3 = slds[wv][i + 3];
#pragma unroll
        for (int j = 0; j < J; j++) {
            if (cc[j] < OUT) {
                float h0 = Hin[(long)s0 * OUT + cc[j]];
                float h1 = Hin[(long)s1 * OUT + cc[j]];
                float h2 = Hin[(long)s2 * OUT + cc[j]];
                float h3 = Hin[(long)s3 * OUT + cc[j]];
                float w0 = wlds[wv][hd[j]][i];
                float w1 = wlds[wv][hd[j]][i + 1];
                float w2 = wlds[wv][hd[j]][i + 2];
                float w3 = wlds[wv][hd[j]][i + 3];
                den[j] += (w0 + w1) + (w2 + w3);
                acc[j] = fmaf(w0, h0, acc[j]); acc[j] = fmaf(w1, h1, acc[j]);
                acc[j] = fmaf(w2, h2, acc[j]); acc[j] = fmaf(w3, h3, acc[j]);
            }
        }
    }
    for (; i < deg; i++) {
        int ss = slds[wv][i];
#pragma unroll
        for (int j = 0; j < J; j++) {
            if (cc[j] < OUT) {
                float w = wlds[wv][hd[j]][i];
                den[j] += w;
                acc[j] = fmaf(w, Hin[(long)ss * OUT + cc[j]], acc[j]);
            }
        }
    }
    if (valid) {
#pragma unroll
        for (int j = 0; j < J; j++) {
            if (cc[j] < OUT) {
                float o = acc[j] / (den[j] + 1e-16f) + bias[cc[j]];
                Oout[(long)n * OUT + cc[j]] = fmaxf(o, 0.f);
            }
        }
    }
}

// ---------------- mean-pool stage 1 (batch sorted: register-accumulate, flush on change) ----------------
__global__ void pool_kernel(const float* __restrict__ O, const int* __restrict__ batch,
                            float* __restrict__ sums, float* __restrict__ counts, int N) {
    int tid = threadIdx.x;                     // 128 threads
    int n0 = blockIdx.x * 512;
    if (n0 >= N) return;
    int nend = min(N, n0 + 512);
    float acc = 0.f; int cl = 0;
    int cur = batch[n0];
    for (int n = n0; n < nend; n++) {
        int g = batch[n];
        if (g != cur) {
            if (tid < 96) atomicAdd(&sums[cur * 96 + tid], acc);
            if (tid == 96) atomicAdd(&counts[cur], (float)cl);
            acc = 0.f; cl = 0; cur = g;
        }
        if (tid < 96) acc += O[(long)n * 96 + tid];
        cl++;
    }
    if (tid < 96) atomicAdd(&sums[cur * 96 + tid], acc);
    if (tid == 96) atomicAdd(&counts[cur], (float)cl);
}

// ---------------- FC head: one block per graph ----------------
__global__ void fc_kernel(const float* __restrict__ sums, const float* __restrict__ counts,
                          const float* __restrict__ W1, const float* __restrict__ b1,
                          const float* __restrict__ W2, const float* __restrict__ b2,
                          float* __restrict__ out) {
    __shared__ float p[96];
    __shared__ float h1[192];
    int g = blockIdx.x, tid = threadIdx.x;     // 192 threads
    if (tid < 96) p[tid] = sums[g * 96 + tid] / fmaxf(counts[g], 1.0f);
    __syncthreads();
    float s = b1[tid];
    for (int c = 0; c < 96; c++) s = fmaf(p[c], W1[c * 192 + tid], s);
    h1[tid] = fmaxf(s, 0.f);
    __syncthreads();
    if (tid < 96) {
        float s2 = b2[tid];
        for (int j = 0; j < 192; j++) s2 = fmaf(h1[j], W2[j * 96 + tid], s2);
        out[g * 96 + tid] = s2;
    }
}

extern "C" void kernel_launch(void* const* d_in, const int* in_sizes, int n_in,
                              void* d_out, int out_size, void* d_ws, size_t ws_size,
                              hipStream_t stream) {
    const float* x     = (const float*)d_in[0];
    const int*   ei    = (const int*)d_in[1];
    const int*   batch = (const int*)d_in[2];
    const float* W0  = (const float*)d_in[3];
    const float* as0 = (const float*)d_in[4];
    const float* ad0 = (const float*)d_in[5];
    const float* b0  = (const float*)d_in[6];
    const float* W1  = (const float*)d_in[7];
    const float* as1 = (const float*)d_in[8];
    const float* ad1 = (const float*)d_in[9];
    const float* b1  = (const float*)d_in[10];
    const float* W2  = (const float*)d_in[11];
    const float* as2 = (const float*)d_in[12];
    const float* ad2 = (const float*)d_in[13];
    const float* b2  = (const float*)d_in[14];
    const float* fcW1 = (const float*)d_in[15];
    const float* fcb1 = (const float*)d_in[16];
    const float* fcW2 = (const float*)d_in[17];
    const float* fcb2 = (const float*)d_in[18];

    const int N = in_sizes[0] / 128;
    const int E = in_sizes[1] / 2;

    char* ws = (char*)d_ws;
    float* Hbuf = (float*)ws;                                   // N*192 f
    float* Obuf = (float*)(ws + (size_t)N * 192 * 4);           // N*192 f
    float* ASRC = (float*)(ws + (size_t)N * 384 * 4);           // N*4 f
    float* ADST = ASRC + (size_t)N * 4;                         // N*4 f
    int*   ADJ  = (int*)(ADST + (size_t)N * 4);                 // N*CAP i
    int*   CNT  = ADJ + (size_t)N * CAP;                        // N i
    float* SUMS = (float*)(CNT + N);                            // 64*96 f
    float* COUNTS = SUMS + 64 * 96;                             // 64 f

    hipMemsetAsync(CNT, 0, ((size_t)N + 64 * 96 + 64) * 4, stream);

    int Et = E + N;
    build_adj_kernel<<<(Et + 255) / 256, 256, 0, stream>>>(ei, E, N, CNT, ADJ);

    int rb = (N + 63) / 64;

    // layer 0: 128 -> 4x48
    gemm_kernel<128, 192><<<dim3(rb, 2), 256, 0, stream>>>(x, W0, Hbuf, N);
    attdot_kernel<4, 192><<<(N * 4 + 255) / 256, 256, 0, stream>>>(Hbuf, as0, ad0, ASRC, ADST, N);
    agg_kernel<192, 4><<<(N + 3) / 4, 256, 0, stream>>>(Hbuf, ASRC, ADST, ADJ, CNT, b0, Obuf, N);

    // layer 1: 192 -> 2x48
    gemm_kernel<192, 96><<<dim3(rb, 1), 256, 0, stream>>>(Obuf, W1, Hbuf, N);
    attdot_kernel<2, 96><<<(N * 2 + 255) / 256, 256, 0, stream>>>(Hbuf, as1, ad1, ASRC, ADST, N);
    agg_kernel<96, 2><<<(N + 3) / 4, 256, 0, stream>>>(Hbuf, ASRC, ADST, ADJ, CNT, b1, Obuf, N);

    // layer 2: 96 -> 2x48
    gemm_kernel<96, 96><<<dim3(rb, 1), 256, 0, stream>>>(Obuf, W2, Hbuf, N);
    attdot_kernel<2, 96><<<(N * 2 + 255) / 256, 256, 0, stream>>>(Hbuf, as2, ad2, ASRC, ADST, N);
    agg_kernel<96, 2><<<(N + 3) / 4, 256, 0, stream>>>(Hbuf, ASRC, ADST, ADJ, CNT, b2, Obuf, N);

    // pooling + FC head
    pool_kernel<<<(N + 511) / 512, 128, 0, stream>>>(Obuf, batch, SUMS, COUNTS, N);
    fc_kernel<<<64, 192, 0, stream>>>(SUMS, COUNTS, fcW1, fcb1, fcW2, fcb2, (float*)d_out);
}

// Round 3
// 736.412 us; speedup vs baseline: 1.4422x; 1.1850x over previous
//
#include <hip/hip_runtime.h>

#define CAP 64
#define DD 48

// ---------------- adjacency build (dst-bucketed, fixed capacity) ----------------
__global__ void build_adj_kernel(const int* __restrict__ ei, int E, int N,
                                 int* __restrict__ cnt, int* __restrict__ adj) {
    int e = blockIdx.x * blockDim.x + threadIdx.x;
    int Et = E + N;
    if (e >= Et) return;
    int s, d;
    if (e < E) { s = ei[e]; d = ei[E + e]; } else { s = e - E; d = e - E; }
    int pos = atomicAdd(&cnt[d], 1);
    if (pos < CAP) adj[d * CAP + pos] = s;
}

// ---------------- fp32 tiled GEMM: Hout[N,NCT] = X[N,K] @ W[K,NCT] ----------------
template<int K, int NCT>
__global__ void gemm_kernel(const float* __restrict__ X, const float* __restrict__ W,
                            float* __restrict__ Hout, int N) {
    __shared__ float XT[32][64];   // k-major x-tile (transposed)
    __shared__ float WS[32][96];
    int tid = threadIdx.x;
    int ty = tid >> 4, tx = tid & 15;
    int rb = blockIdx.x * 64;
    int c0 = blockIdx.y * 96;
    float acc[4][6];
#pragma unroll
    for (int i = 0; i < 4; i++)
#pragma unroll
        for (int j = 0; j < 6; j++) acc[i][j] = 0.f;

    for (int k0 = 0; k0 < K; k0 += 32) {
#pragma unroll
        for (int jj = 0; jj < 2; jj++) {
            int idx = tid + jj * 256;
            int r = idx >> 3, kq = idx & 7;
            int rg = rb + r;
            float4 v = make_float4(0.f, 0.f, 0.f, 0.f);
            if (rg < N) v = *reinterpret_cast<const float4*>(&X[(long)rg * K + k0 + kq * 4]);
            XT[kq * 4 + 0][r] = v.x; XT[kq * 4 + 1][r] = v.y;
            XT[kq * 4 + 2][r] = v.z; XT[kq * 4 + 3][r] = v.w;
        }
#pragma unroll
        for (int jj = 0; jj < 3; jj++) {
            int idx = tid + jj * 256;
            int kr = idx / 24, cq = idx % 24;
            float4 v = *reinterpret_cast<const float4*>(&W[(long)(k0 + kr) * NCT + c0 + cq * 4]);
            *reinterpret_cast<float4*>(&WS[kr][cq * 4]) = v;
        }
        __syncthreads();
#pragma unroll
        for (int kk = 0; kk < 32; kk++) {
            float a[4], b[6];
#pragma unroll
            for (int i = 0; i < 4; i++) a[i] = XT[kk][ty * 4 + i];
#pragma unroll
            for (int j = 0; j < 6; j++) b[j] = WS[kk][tx * 6 + j];
#pragma unroll
            for (int i = 0; i < 4; i++)
#pragma unroll
                for (int j = 0; j < 6; j++) acc[i][j] = fmaf(a[i], b[j], acc[i][j]);
        }
        __syncthreads();
    }
#pragma unroll
    for (int i = 0; i < 4; i++) {
        int r = rb + ty * 4 + i;
        if (r < N) {
#pragma unroll
            for (int j = 0; j < 6; j++)
                Hout[(long)r * NCT + c0 + tx * 6 + j] = acc[i][j];
        }
    }
}

// ---------------- per-(node,head) attention dots ----------------
template<int HEADS, int NCT>
__global__ void attdot_kernel(const float* __restrict__ H, const float* __restrict__ att_s,
                              const float* __restrict__ att_d, float* __restrict__ asrc,
                              float* __restrict__ adst, int N) {
    int idx = blockIdx.x * blockDim.x + threadIdx.x;
    if (idx >= N * HEADS) return;
    int n = idx / HEADS, h = idx % HEADS;
    const float* row = &H[(long)n * (HEADS * DD) + h * DD];
    float s1 = 0.f, s2 = 0.f;
#pragma unroll
    for (int d = 0; d < DD; d++) {
        float v = row[d];
        s1 = fmaf(v, att_s[h * DD + d], s1);
        s2 = fmaf(v, att_d[h * DD + d], s2);
    }
    asrc[idx] = s1;
    adst[idx] = s2;
}

// ---------------- dst-centric fused softmax + aggregate + bias + relu ----------------
// one wave per node; coalesced adjacency load, per-edge weight computed once (LDS
// broadcast), inner loop = independent Hin row-gathers unrolled x4.
template<int OUT, int HEADS>
__global__ void agg_kernel(const float* __restrict__ Hin, const float* __restrict__ asrc,
                           const float* __restrict__ adst, const int* __restrict__ adj,
                           const int* __restrict__ cnt, const float* __restrict__ bias,
                           float* __restrict__ Oout, int N) {
    constexpr int J = (OUT + 63) / 64;
    __shared__ float wlds[4][HEADS][CAP];
    __shared__ int   slds[4][CAP];
    int wv = threadIdx.x >> 6;
    int lane = threadIdx.x & 63;
    int n = blockIdx.x * 4 + wv;
    bool valid = (n < N);
    int nn = valid ? n : 0;
    int deg = min(cnt[nn], CAP);
    int s = (lane < deg) ? adj[nn * CAP + lane] : 0;
    slds[wv][lane] = s;
    if (lane < deg) {
#pragma unroll
        for (int h = 0; h < HEADS; h++) {
            float e = asrc[s * HEADS + h] + adst[nn * HEADS + h];
            e = (e < 0.f) ? 0.2f * e : e;           // leaky_relu, slope 0.2
            wlds[wv][h][lane] = __expf(e);          // max-shift dropped: alpha scale-invariant
        }
    }
    __syncthreads();

    float acc[J], den[J];
    int hd[J], cc[J];
#pragma unroll
    for (int j = 0; j < J; j++) {
        acc[j] = 0.f; den[j] = 0.f;
        cc[j] = lane + 64 * j; hd[j] = cc[j] / DD;
    }
    int i = 0;
    for (; i + 4 <= deg; i += 4) {
        int s0 = slds[wv][i], s1 = slds[wv][i + 1], s2 = slds[wv][i + 2], s3 = slds[wv][i + 3];
#pragma unroll
        for (int j = 0; j < J; j++) {
            if (cc[j] < OUT) {
                float h0 = Hin[(long)s0 * OUT + cc[j]];
                float h1 = Hin[(long)s1 * OUT + cc[j]];
                float h2 = Hin[(long)s2 * OUT + cc[j]];
                float h3 = Hin[(long)s3 * OUT + cc[j]];
                float w0 = wlds[wv][hd[j]][i];
                float w1 = wlds[wv][hd[j]][i + 1];
                float w2 = wlds[wv][hd[j]][i + 2];
                float w3 = wlds[wv][hd[j]][i + 3];
                den[j] += (w0 + w1) + (w2 + w3);
                acc[j] = fmaf(w0, h0, acc[j]); acc[j] = fmaf(w1, h1, acc[j]);
                acc[j] = fmaf(w2, h2, acc[j]); acc[j] = fmaf(w3, h3, acc[j]);
            }
        }
    }
    for (; i < deg; i++) {
        int ss = slds[wv][i];
#pragma unroll
        for (int j = 0; j < J; j++) {
            if (cc[j] < OUT) {
                float w = wlds[wv][hd[j]][i];
                den[j] += w;
                acc[j] = fmaf(w, Hin[(long)ss * OUT + cc[j]], acc[j]);
            }
        }
    }
    if (valid) {
#pragma unroll
        for (int j = 0; j < J; j++) {
            if (cc[j] < OUT) {
                float o = acc[j] / (den[j] + 1e-16f) + bias[cc[j]];
                Oout[(long)n * OUT + cc[j]] = fmaxf(o, 0.f);
            }
        }
    }
}

// ---------------- mean-pool (R3): 128-thread groups, 64-node contiguous chunks,
// 4x-unrolled independent loads; sorted batch => rare boundary flushes ----------------
__global__ void pool_kernel(const float* __restrict__ O, const int* __restrict__ batch,
                            float* __restrict__ sums, float* __restrict__ counts, int N) {
    int grp = threadIdx.x >> 7;                 // 4 groups of 128 per block
    int c = threadIdx.x & 127;                  // channel lane; active if < 96
    int n0 = (blockIdx.x * 4 + grp) * 64;
    if (n0 >= N) return;
    int nend = min(N, n0 + 64);
    bool act = (c < 96);
    float acc = 0.f; int cl = 0;
    int cur = batch[n0];
    int n = n0;
    for (; n + 4 <= nend; n += 4) {
        int g0 = batch[n], g1 = batch[n + 1], g2 = batch[n + 2], g3 = batch[n + 3];
        float v0 = 0.f, v1 = 0.f, v2 = 0.f, v3 = 0.f;
        if (act) {
            v0 = O[(long)n * 96 + c];       v1 = O[(long)(n + 1) * 96 + c];
            v2 = O[(long)(n + 2) * 96 + c]; v3 = O[(long)(n + 3) * 96 + c];
        }
#define POOL_STEP(g, v)                                                        \
        if ((g) != cur) {                                                      \
            if (act) atomicAdd(&sums[cur * 96 + c], acc);                      \
            if (c == 96) atomicAdd(&counts[cur], (float)cl);                   \
            acc = 0.f; cl = 0; cur = (g);                                      \
        }                                                                      \
        acc += (v); cl++;
        POOL_STEP(g0, v0) POOL_STEP(g1, v1) POOL_STEP(g2, v2) POOL_STEP(g3, v3)
    }
    for (; n < nend; n++) {
        int g = batch[n];
        float v = act ? O[(long)n * 96 + c] : 0.f;
        POOL_STEP(g, v)
    }
#undef POOL_STEP
    if (act) atomicAdd(&sums[cur * 96 + c], acc);
    if (c == 96) atomicAdd(&counts[cur], (float)cl);
}

// ---------------- FC head: one block per graph ----------------
__global__ void fc_kernel(const float* __restrict__ sums, const float* __restrict__ counts,
                          const float* __restrict__ W1, const float* __restrict__ b1,
                          const float* __restrict__ W2, const float* __restrict__ b2,
                          float* __restrict__ out) {
    __shared__ float p[96];
    __shared__ float h1[192];
    int g = blockIdx.x, tid = threadIdx.x;     // 192 threads
    if (tid < 96) p[tid] = sums[g * 96 + tid] / fmaxf(counts[g], 1.0f);
    __syncthreads();
    float s = b1[tid];
    for (int c = 0; c < 96; c++) s = fmaf(p[c], W1[c * 192 + tid], s);
    h1[tid] = fmaxf(s, 0.f);
    __syncthreads();
    if (tid < 96) {
        float s2 = b2[tid];
        for (int j = 0; j < 192; j++) s2 = fmaf(h1[j], W2[j * 96 + tid], s2);
        out[g * 96 + tid] = s2;
    }
}

extern "C" void kernel_launch(void* const* d_in, const int* in_sizes, int n_in,
                              void* d_out, int out_size, void* d_ws, size_t ws_size,
                              hipStream_t stream) {
    const float* x     = (const float*)d_in[0];
    const int*   ei    = (const int*)d_in[1];
    const int*   batch = (const int*)d_in[2];
    const float* W0  = (const float*)d_in[3];
    const float* as0 = (const float*)d_in[4];
    const float* ad0 = (const float*)d_in[5];
    const float* b0  = (const float*)d_in[6];
    const float* W1  = (const float*)d_in[7];
    const float* as1 = (const float*)d_in[8];
    const float* ad1 = (const float*)d_in[9];
    const float* b1  = (const float*)d_in[10];
    const float* W2  = (const float*)d_in[11];
    const float* as2 = (const float*)d_in[12];
    const float* ad2 = (const float*)d_in[13];
    const float* b2  = (const float*)d_in[14];
    const float* fcW1 = (const float*)d_in[15];
    const float* fcb1 = (const float*)d_in[16];
    const float* fcW2 = (const float*)d_in[17];
    const float* fcb2 = (const float*)d_in[18];

    const int N = in_sizes[0] / 128;
    const int E = in_sizes[1] / 2;

    char* ws = (char*)d_ws;
    float* Hbuf = (float*)ws;                                   // N*192 f
    float* Obuf = (float*)(ws + (size_t)N * 192 * 4);           // N*192 f
    float* ASRC = (float*)(ws + (size_t)N * 384 * 4);           // N*4 f
    float* ADST = ASRC + (size_t)N * 4;                         // N*4 f
    int*   ADJ  = (int*)(ADST + (size_t)N * 4);                 // N*CAP i
    int*   CNT  = ADJ + (size_t)N * CAP;                        // N i
    float* SUMS = (float*)(CNT + N);                            // 64*96 f
    float* COUNTS = SUMS + 64 * 96;                             // 64 f

    hipMemsetAsync(CNT, 0, ((size_t)N + 64 * 96 + 64) * 4, stream);

    int Et = E + N;
    build_adj_kernel<<<(Et + 255) / 256, 256, 0, stream>>>(ei, E, N, CNT, ADJ);

    int rb = (N + 63) / 64;

    // layer 0: 128 -> 4x48
    gemm_kernel<128, 192><<<dim3(rb, 2), 256, 0, stream>>>(x, W0, Hbuf, N);
    attdot_kernel<4, 192><<<(N * 4 + 255) / 256, 256, 0, stream>>>(Hbuf, as0, ad0, ASRC, ADST, N);
    agg_kernel<192, 4><<<(N + 3) / 4, 256, 0, stream>>>(Hbuf, ASRC, ADST, ADJ, CNT, b0, Obuf, N);

    // layer 1: 192 -> 2x48
    gemm_kernel<192, 96><<<dim3(rb, 1), 256, 0, stream>>>(Obuf, W1, Hbuf, N);
    attdot_kernel<2, 96><<<(N * 2 + 255) / 256, 256, 0, stream>>>(Hbuf, as1, ad1, ASRC, ADST, N);
    agg_kernel<96, 2><<<(N + 3) / 4, 256, 0, stream>>>(Hbuf, ASRC, ADST, ADJ, CNT, b1, Obuf, N);

    // layer 2: 96 -> 2x48
    gemm_kernel<96, 96><<<dim3(rb, 1), 256, 0, stream>>>(Obuf, W2, Hbuf, N);
    attdot_kernel<2, 96><<<(N * 2 + 255) / 256, 256, 0, stream>>>(Hbuf, as2, ad2, ASRC, ADST, N);
    agg_kernel<96, 2><<<(N + 3) / 4, 256, 0, stream>>>(Hbuf, ASRC, ADST, ADJ, CNT, b2, Obuf, N);

    // pooling + FC head
    pool_kernel<<<(N / 256) + 1, 512, 0, stream>>>(Obuf, batch, SUMS, COUNTS, N);
    fc_kernel<<<64, 192, 0, stream>>>(SUMS, COUNTS, fcW1, fcb1, fcW2, fcb2, (float*)d_out);
}

// Round 4
// 667.376 us; speedup vs baseline: 1.5913x; 1.1034x over previous
//
#include <hip/hip_runtime.h>

#define CAP 64
#define DD 48

// ---------------- adjacency build (dst-bucketed, fixed capacity) ----------------
__global__ void build_adj_kernel(const int* __restrict__ ei, int E, int N,
                                 int* __restrict__ cnt, int* __restrict__ adj) {
    int e = blockIdx.x * blockDim.x + threadIdx.x;
    int Et = E + N;
    if (e >= Et) return;
    int s, d;
    if (e < E) { s = ei[e]; d = ei[E + e]; } else { s = e - E; d = e - E; }
    int pos = atomicAdd(&cnt[d], 1);
    if (pos < CAP) adj[d * CAP + pos] = s;
}

// ---------------- fp32 tiled GEMM + fused attention dots ----------------
// Hout[N,NCT] = X[N,K] @ W[K,NCT]; also asrc/adst[n,h] = sum_d Hout[n,h*48+d]*att[h][d].
// block tile 64x96, K-tile 32, 256 threads (16x16), thread tile 4x6.
// Head boundary at 48 cols = tx subgroups 0-7 / 8-15 (6-wide chunks never straddle).
template<int K, int NCT, int HEADS>
__global__ void gemm_kernel(const float* __restrict__ X, const float* __restrict__ W,
                            const float* __restrict__ att_s, const float* __restrict__ att_d,
                            float* __restrict__ Hout, float* __restrict__ asrc,
                            float* __restrict__ adst, int N) {
    __shared__ float XT[32][64];   // k-major x-tile (transposed)
    __shared__ float WS[32][96];
    int tid = threadIdx.x;
    int ty = tid >> 4, tx = tid & 15;
    int rb = blockIdx.x * 64;
    int c0 = blockIdx.y * 96;
    float acc[4][6];
#pragma unroll
    for (int i = 0; i < 4; i++)
#pragma unroll
        for (int j = 0; j < 6; j++) acc[i][j] = 0.f;

    for (int k0 = 0; k0 < K; k0 += 32) {
#pragma unroll
        for (int jj = 0; jj < 2; jj++) {
            int idx = tid + jj * 256;
            int r = idx >> 3, kq = idx & 7;
            int rg = rb + r;
            float4 v = make_float4(0.f, 0.f, 0.f, 0.f);
            if (rg < N) v = *reinterpret_cast<const float4*>(&X[(long)rg * K + k0 + kq * 4]);
            XT[kq * 4 + 0][r] = v.x; XT[kq * 4 + 1][r] = v.y;
            XT[kq * 4 + 2][r] = v.z; XT[kq * 4 + 3][r] = v.w;
        }
#pragma unroll
        for (int jj = 0; jj < 3; jj++) {
            int idx = tid + jj * 256;
            int kr = idx / 24, cq = idx % 24;
            float4 v = *reinterpret_cast<const float4*>(&W[(long)(k0 + kr) * NCT + c0 + cq * 4]);
            *reinterpret_cast<float4*>(&WS[kr][cq * 4]) = v;
        }
        __syncthreads();
#pragma unroll
        for (int kk = 0; kk < 32; kk++) {
            float a[4], b[6];
#pragma unroll
            for (int i = 0; i < 4; i++) a[i] = XT[kk][ty * 4 + i];
#pragma unroll
            for (int j = 0; j < 6; j++) b[j] = WS[kk][tx * 6 + j];
#pragma unroll
            for (int i = 0; i < 4; i++)
#pragma unroll
                for (int j = 0; j < 6; j++) acc[i][j] = fmaf(a[i], b[j], acc[i][j]);
        }
        __syncthreads();
    }
#pragma unroll
    for (int i = 0; i < 4; i++) {
        int r = rb + ty * 4 + i;
        if (r < N) {
#pragma unroll
            for (int j = 0; j < 6; j++)
                Hout[(long)r * NCT + c0 + tx * 6 + j] = acc[i][j];
        }
    }

    // ---- fused attention dots ----
    int hl = tx >> 3;                        // local head within 96-col block
    int head = (c0 / DD) + hl;
    int cih = tx * 6 - hl * DD;              // col-in-head base
    float ps[4] = {0.f, 0.f, 0.f, 0.f};
    float pd[4] = {0.f, 0.f, 0.f, 0.f};
#pragma unroll
    for (int j = 0; j < 6; j++) {
        float asv = att_s[head * DD + cih + j];
        float adv = att_d[head * DD + cih + j];
#pragma unroll
        for (int i = 0; i < 4; i++) {
            ps[i] = fmaf(acc[i][j], asv, ps[i]);
            pd[i] = fmaf(acc[i][j], adv, pd[i]);
        }
    }
#pragma unroll
    for (int i = 0; i < 4; i++) {
#pragma unroll
        for (int d = 1; d < 8; d <<= 1) {
            ps[i] += __shfl_xor(ps[i], d);
            pd[i] += __shfl_xor(pd[i], d);
        }
    }
    if ((tx & 7) == 0) {
#pragma unroll
        for (int i = 0; i < 4; i++) {
            int r = rb + ty * 4 + i;
            if (r < N) {
                asrc[r * HEADS + head] = ps[i];
                adst[r * HEADS + head] = pd[i];
            }
        }
    }
}

// ---------------- dst-centric fused softmax + aggregate + bias + relu ----------------
// one wave per node. Lane owns VEC consecutive channels (one dwordx{2,4} gather/edge),
// per-edge weight computed once (all 64 lanes, LDS broadcast), denominator hoisted to
// a per-head wave reduction, inner loop unrolled x8 (8 wide gathers in flight).
template<int OUT, int HEADS, int VEC>
__global__ void agg_kernel(const float* __restrict__ Hin, const float* __restrict__ asrc,
                           const float* __restrict__ adst, const int* __restrict__ adj,
                           const int* __restrict__ cnt, const float* __restrict__ bias,
                           float* __restrict__ Oout, int N) {
    typedef float vec_t __attribute__((ext_vector_type(VEC)));
    constexpr int NL = OUT / VEC;            // active gather lanes (48)
    __shared__ float wlds[4][HEADS][CAP];
    __shared__ float dlds[4][HEADS];
    __shared__ int   slds[4][CAP];
    int wv = threadIdx.x >> 6;
    int lane = threadIdx.x & 63;
    int n = blockIdx.x * 4 + wv;
    bool valid = (n < N);
    int nn = valid ? n : 0;
    int deg = min(cnt[nn], CAP);
    int s = (lane < deg) ? adj[nn * CAP + lane] : 0;
    slds[wv][lane] = s;
    float w[HEADS];
#pragma unroll
    for (int h = 0; h < HEADS; h++) {
        float e = asrc[s * HEADS + h] + adst[nn * HEADS + h];
        e = (e < 0.f) ? 0.2f * e : e;               // leaky_relu, slope 0.2
        w[h] = (lane < deg) ? __expf(e) : 0.f;      // max-shift dropped: scale-invariant
        wlds[wv][h][lane] = w[h];
    }
#pragma unroll
    for (int h = 0; h < HEADS; h++) {               // den = wave-sum of weights
        float dsum = w[h];
#pragma unroll
        for (int off = 1; off < 64; off <<= 1) dsum += __shfl_xor(dsum, off);
        if (lane == 0) dlds[wv][h] = dsum;
    }
    __syncthreads();

    bool act = (lane < NL);
    int c = act ? lane * VEC : 0;                   // idle lanes alias lane0's line
    int head = c / DD;
    const float* wrow = wlds[wv][head];
    vec_t acc;
#pragma unroll
    for (int k = 0; k < VEC; k++) acc[k] = 0.f;

    int i = 0;
    for (; i + 8 <= deg; i += 8) {
        int sv[8];
#pragma unroll
        for (int u = 0; u < 8; u++) sv[u] = slds[wv][i + u];
        vec_t hv[8];
#pragma unroll
        for (int u = 0; u < 8; u++)
            hv[u] = *reinterpret_cast<const vec_t*>(&Hin[(long)sv[u] * OUT + c]);
#pragma unroll
        for (int u = 0; u < 8; u++) {
            float ww = wrow[i + u];
#pragma unroll
            for (int k = 0; k < VEC; k++) acc[k] = fmaf(ww, hv[u][k], acc[k]);
        }
    }
    for (; i < deg; i++) {
        int ss = slds[wv][i];
        vec_t hv = *reinterpret_cast<const vec_t*>(&Hin[(long)ss * OUT + c]);
        float ww = wrow[i];
#pragma unroll
        for (int k = 0; k < VEC; k++) acc[k] = fmaf(ww, hv[k], acc[k]);
    }

    if (valid && act) {
        float invd = 1.f / (dlds[wv][head] + 1e-16f);
        vec_t o;
#pragma unroll
        for (int k = 0; k < VEC; k++) o[k] = fmaxf(fmaf(acc[k], invd, bias[c + k]), 0.f);
        *reinterpret_cast<vec_t*>(&Oout[(long)n * OUT + c]) = o;
    }
}

// ---------------- mean-pool: 128-thread groups, 64-node chunks, 4x-unrolled ----------------
__global__ void pool_kernel(const float* __restrict__ O, const int* __restrict__ batch,
                            float* __restrict__ sums, float* __restrict__ counts, int N) {
    int grp = threadIdx.x >> 7;                 // 4 groups of 128 per block
    int c = threadIdx.x & 127;                  // channel lane; active if < 96
    int n0 = (blockIdx.x * 4 + grp) * 64;
    if (n0 >= N) return;
    int nend = min(N, n0 + 64);
    bool act = (c < 96);
    float acc = 0.f; int cl = 0;
    int cur = batch[n0];
    int n = n0;
    for (; n + 4 <= nend; n += 4) {
        int g0 = batch[n], g1 = batch[n + 1], g2 = batch[n + 2], g3 = batch[n + 3];
        float v0 = 0.f, v1 = 0.f, v2 = 0.f, v3 = 0.f;
        if (act) {
            v0 = O[(long)n * 96 + c];       v1 = O[(long)(n + 1) * 96 + c];
            v2 = O[(long)(n + 2) * 96 + c]; v3 = O[(long)(n + 3) * 96 + c];
        }
#define POOL_STEP(g, v)                                                        \
        if ((g) != cur) {                                                      \
            if (act) atomicAdd(&sums[cur * 96 + c], acc);                      \
            if (c == 96) atomicAdd(&counts[cur], (float)cl);                   \
            acc = 0.f; cl = 0; cur = (g);                                      \
        }                                                                      \
        acc += (v); cl++;
        POOL_STEP(g0, v0) POOL_STEP(g1, v1) POOL_STEP(g2, v2) POOL_STEP(g3, v3)
    }
    for (; n < nend; n++) {
        int g = batch[n];
        float v = act ? O[(long)n * 96 + c] : 0.f;
        POOL_STEP(g, v)
    }
#undef POOL_STEP
    if (act) atomicAdd(&sums[cur * 96 + c], acc);
    if (c == 96) atomicAdd(&counts[cur], (float)cl);
}

// ---------------- FC head: one block per graph ----------------
__global__ void fc_kernel(const float* __restrict__ sums, const float* __restrict__ counts,
                          const float* __restrict__ W1, const float* __restrict__ b1,
                          const float* __restrict__ W2, const float* __restrict__ b2,
                          float* __restrict__ out) {
    __shared__ float p[96];
    __shared__ float h1[192];
    int g = blockIdx.x, tid = threadIdx.x;     // 192 threads
    if (tid < 96) p[tid] = sums[g * 96 + tid] / fmaxf(counts[g], 1.0f);
    __syncthreads();
    float s = b1[tid];
    for (int c = 0; c < 96; c++) s = fmaf(p[c], W1[c * 192 + tid], s);
    h1[tid] = fmaxf(s, 0.f);
    __syncthreads();
    if (tid < 96) {
        float s2 = b2[tid];
        for (int j = 0; j < 192; j++) s2 = fmaf(h1[j], W2[j * 96 + tid], s2);
        out[g * 96 + tid] = s2;
    }
}

extern "C" void kernel_launch(void* const* d_in, const int* in_sizes, int n_in,
                              void* d_out, int out_size, void* d_ws, size_t ws_size,
                              hipStream_t stream) {
    const float* x     = (const float*)d_in[0];
    const int*   ei    = (const int*)d_in[1];
    const int*   batch = (const int*)d_in[2];
    const float* W0  = (const float*)d_in[3];
    const float* as0 = (const float*)d_in[4];
    const float* ad0 = (const float*)d_in[5];
    const float* b0  = (const float*)d_in[6];
    const float* W1  = (const float*)d_in[7];
    const float* as1 = (const float*)d_in[8];
    const float* ad1 = (const float*)d_in[9];
    const float* b1  = (const float*)d_in[10];
    const float* W2  = (const float*)d_in[11];
    const float* as2 = (const float*)d_in[12];
    const float* ad2 = (const float*)d_in[13];
    const float* b2  = (const float*)d_in[14];
    const float* fcW1 = (const float*)d_in[15];
    const float* fcb1 = (const float*)d_in[16];
    const float* fcW2 = (const float*)d_in[17];
    const float* fcb2 = (const float*)d_in[18];

    const int N = in_sizes[0] / 128;
    const int E = in_sizes[1] / 2;

    char* ws = (char*)d_ws;
    float* Hbuf = (float*)ws;                                   // N*192 f
    float* Obuf = (float*)(ws + (size_t)N * 192 * 4);           // N*192 f
    float* ASRC = (float*)(ws + (size_t)N * 384 * 4);           // N*4 f
    float* ADST = ASRC + (size_t)N * 4;                         // N*4 f
    int*   ADJ  = (int*)(ADST + (size_t)N * 4);                 // N*CAP i
    int*   CNT  = ADJ + (size_t)N * CAP;                        // N i
    float* SUMS = (float*)(CNT + N);                            // 64*96 f
    float* COUNTS = SUMS + 64 * 96;                             // 64 f

    hipMemsetAsync(CNT, 0, ((size_t)N + 64 * 96 + 64) * 4, stream);

    int Et = E + N;
    build_adj_kernel<<<(Et + 255) / 256, 256, 0, stream>>>(ei, E, N, CNT, ADJ);

    int rb = (N + 63) / 64;

    // layer 0: 128 -> 4x48
    gemm_kernel<128, 192, 4><<<dim3(rb, 2), 256, 0, stream>>>(x, W0, as0, ad0, Hbuf, ASRC, ADST, N);
    agg_kernel<192, 4, 4><<<(N + 3) / 4, 256, 0, stream>>>(Hbuf, ASRC, ADST, ADJ, CNT, b0, Obuf, N);

    // layer 1: 192 -> 2x48
    gemm_kernel<192, 96, 2><<<dim3(rb, 1), 256, 0, stream>>>(Obuf, W1, as1, ad1, Hbuf, ASRC, ADST, N);
    agg_kernel<96, 2, 2><<<(N + 3) / 4, 256, 0, stream>>>(Hbuf, ASRC, ADST, ADJ, CNT, b1, Obuf, N);

    // layer 2: 96 -> 2x48
    gemm_kernel<96, 96, 2><<<dim3(rb, 1), 256, 0, stream>>>(Obuf, W2, as2, ad2, Hbuf, ASRC, ADST, N);
    agg_kernel<96, 2, 2><<<(N + 3) / 4, 256, 0, stream>>>(Hbuf, ASRC, ADST, ADJ, CNT, b2, Obuf, N);

    // pooling + FC head
    pool_kernel<<<(N / 256) + 1, 512, 0, stream>>>(Obuf, batch, SUMS, COUNTS, N);
    fc_kernel<<<64, 192, 0, stream>>>(SUMS, COUNTS, fcW1, fcb1, fcW2, fcb2, (float*)d_out);
}